// Round 4
// baseline (148.429 us; speedup 1.0000x reference)
//
#include <hip/hip_runtime.h>

#define B_  16
#define LC  2048
#define LQ  512
#define DD  128
#define L2E 1.44269504088896340736f
#define SP  16

typedef __attribute__((ext_vector_type(8))) short bf16x8;
typedef __attribute__((ext_vector_type(4))) float f32x4;
typedef unsigned short u16;
typedef unsigned int   u32;

#define MFMA(a,b,c) __builtin_amdgcn_mfma_f32_16x16x32_bf16((a),(b),(c),0,0,0)

__device__ __forceinline__ u16 f2bf(float x){
  u32 u = __builtin_bit_cast(u32, x);
  u32 r = (u + 0x7FFFu + ((u >> 16) & 1u)) >> 16;
  return (u16)r;
}
__device__ __forceinline__ float bf2f(u16 h){
  u32 u = ((u32)h) << 16;
  return __builtin_bit_cast(float, u);
}
__device__ __forceinline__ bf16x8 ldb8(const u16* p){
  return *reinterpret_cast<const bf16x8*>(p);
}
// swizzled LDS read addr for a [rows][256B] tile: byte ^= (row&7)<<4
__device__ __forceinline__ const u16* swz(const u16* base, int row, int colb){
  return base + (row << 7) + ((colb ^ ((row & 7) << 4)) >> 1);
}
// swizzled LDS addr for a [rows][1024B] tile
__device__ __forceinline__ u16* swzP(u16* base, int row, int colb){
  return base + (row << 9) + ((colb ^ ((row & 7) << 4)) >> 1);
}
#define GLOAD_LDS(g, l) \
  __builtin_amdgcn_global_load_lds((const __attribute__((address_space(1))) void*)(g), \
                                   (__attribute__((address_space(3))) void*)(l), 16, 0, 0)

// ---------------- K0: bf16 staging + transposes + row-dots ----------------
__global__ void prep(const float* __restrict__ C, const float* __restrict__ Q,
                     const float* __restrict__ w4C, const float* __restrict__ w4Q,
                     const float* __restrict__ w4mlu,
                     u16* __restrict__ Cwb, u16* __restrict__ CbT,
                     u16* __restrict__ Qb,  u16* __restrict__ QbT,
                     float* __restrict__ sub0, float* __restrict__ sub1){
  __shared__ u16 tile[64][130];
  __shared__ float wl[128];
  int t = threadIdx.x, blk = blockIdx.x;
  int lane = t & 63;
  bool isC = blk < 512;
  if (t < 128) wl[t] = w4mlu[t];
  __syncthreads();
  float2 wv = reinterpret_cast<const float2*>(isC ? w4C : w4Q)[lane];
  if (isC) {
    int b = blk >> 5, ct = blk & 31, c0 = ct << 6;
    const float* src = C + ((size_t)(b*LC + c0))*DD;
    for (int k = 0; k < 16; ++k) {
      int idx = t + (k << 8);
      int r = idx >> 6, d2 = idx & 63;
      float2 v = reinterpret_cast<const float2*>(src + (size_t)r*DD)[d2];
      float sdot = v.x*wv.x + v.y*wv.y;
      #pragma unroll
      for (int o = 32; o > 0; o >>= 1) sdot += __shfl_xor(sdot, o);
      if (lane == 0) sub0[b*LC + c0 + r] = sdot;
      float cw0 = v.x * wl[2*d2], cw1 = v.y * wl[2*d2+1];
      size_t o = ((size_t)(b*LC + c0 + r))*DD + 2*d2;
      *reinterpret_cast<u32*>(Cwb + o) = (u32)f2bf(cw0) | ((u32)f2bf(cw1) << 16);
      tile[r][2*d2]   = f2bf(v.x);
      tile[r][2*d2+1] = f2bf(v.y);
    }
    __syncthreads();
    for (int k = 0; k < 8; ++k) {
      int ch = t + (k << 8);
      int d = ch >> 4, c4 = (ch & 15) << 2;
      u32 lo = (u32)tile[c4][d]   | ((u32)tile[c4+1][d] << 16);
      u32 hi = (u32)tile[c4+2][d] | ((u32)tile[c4+3][d] << 16);
      uint2 u; u.x = lo; u.y = hi;
      *reinterpret_cast<uint2*>(CbT + ((size_t)(b*DD + d))*LC + c0 + c4) = u;
    }
  } else {
    int bq = blk - 512;
    int b = bq >> 3, qt = bq & 7, q0 = qt << 6;
    const float* src = Q + ((size_t)(b*LQ + q0))*DD;
    for (int k = 0; k < 16; ++k) {
      int idx = t + (k << 8);
      int r = idx >> 6, d2 = idx & 63;
      float2 v = reinterpret_cast<const float2*>(src + (size_t)r*DD)[d2];
      float sdot = v.x*wv.x + v.y*wv.y;
      #pragma unroll
      for (int o = 32; o > 0; o >>= 1) sdot += __shfl_xor(sdot, o);
      if (lane == 0) sub1[b*LQ + q0 + r] = sdot;
      u16 h0 = f2bf(v.x), h1 = f2bf(v.y);
      size_t o = ((size_t)(b*LQ + q0 + r))*DD + 2*d2;
      *reinterpret_cast<u32*>(Qb + o) = (u32)h0 | ((u32)h1 << 16);
      tile[r][2*d2]   = h0;
      tile[r][2*d2+1] = h1;
    }
    __syncthreads();
    for (int k = 0; k < 8; ++k) {
      int ch = t + (k << 8);
      int d = ch >> 4, c4 = (ch & 15) << 2;
      u32 lo = (u32)tile[c4][d]   | ((u32)tile[c4+1][d] << 16);
      u32 hi = (u32)tile[c4+2][d] | ((u32)tile[c4+3][d] << 16);
      uint2 u; u.x = lo; u.y = hi;
      *reinterpret_cast<uint2*>(QbT + ((size_t)(b*DD + d))*LQ + q0 + c4) = u;
    }
  }
}

// ---------------- K1: flash column-softmax -> partial T ----------------
__global__ __launch_bounds__(256, 3)
void flashT(const u16* __restrict__ Qb, const u16* __restrict__ Cwb,
            const u16* __restrict__ CbT, const float* __restrict__ sub0,
            float* __restrict__ mPart, float* __restrict__ lPart,
            u16* __restrict__ TaccP){
  __shared__ __align__(16) u16 buf[128*128];
  __shared__ u16 Pl[64][136];
  int bid = blockIdx.x;
  int id = (bid & 7) * 256 + (bid >> 3);
  int b = id >> 7, qb = (id >> 4) & 7, sp = id & 15;
  int c0 = sp * 128;
  int w = threadIdx.x >> 6, l = threadIdx.x & 63;
  int lj = l & 15, lg = l >> 4;

  {
    const char* gb = (const char*)(Cwb + ((size_t)(b*LC + c0))*DD);
    #pragma unroll
    for (int i = 0; i < 8; ++i) {
      int off = (w*8 + i)*1024 + l*16;
      int row = off >> 8, col = off & 255;
      int src = (row << 8) | (col ^ ((row & 7) << 4));
      GLOAD_LDS(gb + src, (char*)buf + off);
    }
  }
  const u16* Qrow = Qb + ((size_t)(b*LQ + qb*64 + w*16 + lj))*DD;
  bf16x8 aq[4];
  #pragma unroll
  for (int k = 0; k < 4; ++k) aq[k] = ldb8(Qrow + k*32 + lg*8);
  float s0v[8];
  #pragma unroll
  for (int f = 0; f < 8; ++f) s0v[f] = sub0[b*LC + c0 + f*16 + lj];
  __syncthreads();

  f32x4 s[8];
  #pragma unroll
  for (int f = 0; f < 8; ++f) s[f] = (f32x4){0.f,0.f,0.f,0.f};
  #pragma unroll
  for (int ks = 0; ks < 4; ++ks) {
    #pragma unroll
    for (int f = 0; f < 8; ++f)
      s[f] = MFMA(aq[ks], ldb8(swz(buf, f*16 + lj, ks*64 + lg*16)), s[f]);
  }
  __syncthreads();

  {
    const char* gb = (const char*)CbT + ((size_t)b*DD)*LC*2 + (size_t)c0*2;
    #pragma unroll
    for (int i = 0; i < 8; ++i) {
      int off = (w*8 + i)*1024 + l*16;
      int row = off >> 8, col = off & 255;
      size_t src = (size_t)row*(LC*2) + (col ^ ((row & 7) << 4));
      GLOAD_LDS(gb + src, (char*)buf + off);
    }
  }

  float tm[4] = {-1e30f,-1e30f,-1e30f,-1e30f};
  #pragma unroll
  for (int f = 0; f < 8; ++f) {
    #pragma unroll
    for (int r = 0; r < 4; ++r) { s[f][r] += s0v[f]; tm[r] = fmaxf(tm[r], s[f][r]); }
  }
  #pragma unroll
  for (int r = 0; r < 4; ++r) {
    #pragma unroll
    for (int m = 1; m < 16; m <<= 1) tm[r] = fmaxf(tm[r], __shfl_xor(tm[r], m));
  }
  float psum[4] = {0.f,0.f,0.f,0.f};
  #pragma unroll
  for (int f = 0; f < 8; ++f) {
    #pragma unroll
    for (int r = 0; r < 4; ++r) {
      float p = exp2f((s[f][r] - tm[r]) * L2E);
      psum[r] += p;
      Pl[w*16 + lg*4 + r][f*16 + lj] = f2bf(p);
    }
  }
  #pragma unroll
  for (int r = 0; r < 4; ++r) {
    #pragma unroll
    for (int m = 1; m < 16; m <<= 1) psum[r] += __shfl_xor(psum[r], m);
  }
  int pbase = (b*8 + qb)*SP + sp;
  if (lj == 0) {
    #pragma unroll
    for (int r = 0; r < 4; ++r) {
      mPart[pbase*64 + w*16 + lg*4 + r] = tm[r];
      lPart[pbase*64 + w*16 + lg*4 + r] = psum[r];
    }
  }
  __syncthreads();

  f32x4 tacc[8];
  #pragma unroll
  for (int f = 0; f < 8; ++f) tacc[f] = (f32x4){0.f,0.f,0.f,0.f};
  #pragma unroll
  for (int ks = 0; ks < 4; ++ks) {
    bf16x8 ap = *reinterpret_cast<const bf16x8*>(&Pl[w*16 + lj][ks*32 + lg*8]);
    #pragma unroll
    for (int f = 0; f < 8; ++f)
      tacc[f] = MFMA(ap, ldb8(swz(buf, f*16 + lj, ks*64 + lg*16)), tacc[f]);
  }
  #pragma unroll
  for (int f = 0; f < 8; ++f) {
    ushort4 hv;
    hv.x = f2bf(tacc[f][0]); hv.y = f2bf(tacc[f][1]);
    hv.z = f2bf(tacc[f][2]); hv.w = f2bf(tacc[f][3]);
    *reinterpret_cast<ushort4*>(TaccP + (((size_t)pbase*4 + w)*8 + f)*256 + lj*16 + lg*4) = hv;
  }
}

// ---------------- K1b: combine c-split partials -> TbT ----------------
__global__ void combineT(const float* __restrict__ mPart, const float* __restrict__ lPart,
                         const u16* __restrict__ TaccP, u16* __restrict__ TbT){
  __shared__ float fac[SP][64];
  __shared__ u16 Tt[64][68];
  int blk = blockIdx.x;
  int b = blk >> 4, qb = (blk >> 1) & 7, dh = blk & 1;
  int t = threadIdx.x;
  int base = (b*8 + qb)*SP;
  if (t < 64) {
    float m_[SP], mm = -1e30f;
    #pragma unroll
    for (int p = 0; p < SP; ++p) { m_[p] = mPart[(base+p)*64 + t]; mm = fmaxf(mm, m_[p]); }
    float lt = 0.f, e[SP];
    #pragma unroll
    for (int p = 0; p < SP; ++p) {
      e[p] = exp2f((m_[p] - mm) * L2E);
      lt += lPart[(base+p)*64 + t] * e[p];
    }
    float il = 1.0f / lt;
    #pragma unroll
    for (int p = 0; p < SP; ++p) fac[p][t] = e[p] * il;
  }
  __syncthreads();
  int lj = t >> 4, lg = (t >> 2) & 3, r = t & 3;
  for (int w = 0; w < 4; ++w) {
    int q = w*16 + lg*4 + r;
    for (int fi = 0; fi < 4; ++fi) {
      int f = dh*4 + fi;
      float acc = 0.f;
      #pragma unroll
      for (int p = 0; p < SP; ++p)
        acc += bf2f(TaccP[(((size_t)(base+p)*4 + w)*8 + f)*256 + t]) * fac[p][q];
      Tt[q][fi*16 + lj] = f2bf(acc);
    }
  }
  __syncthreads();
  for (int k = 0; k < 4; ++k) {
    int ch = t + (k << 8); int dl = ch >> 4, q4 = (ch & 15) << 2;
    u32 lo = (u32)Tt[q4][dl]   | ((u32)Tt[q4+1][dl] << 16);
    u32 hi = (u32)Tt[q4+2][dl] | ((u32)Tt[q4+3][dl] << 16);
    uint2 u; u.x = lo; u.y = hi;
    *reinterpret_cast<uint2*>(TbT + ((size_t)(b*DD + dh*64 + dl))*LQ + qb*64 + q4) = u;
  }
}

// ---------------- K2: row-softmax + A + Bt + epilogue ----------------
// grid 1024 = 16 b x 64 ctiles(32 c). 8 waves (512 thr): wc = c-half, wq = q-quarter.
__global__ __launch_bounds__(512, 4)
void fused_out(const float* __restrict__ Cf, const u16* __restrict__ Cwb,
               const u16* __restrict__ Qb, const u16* __restrict__ QbT,
               const u16* __restrict__ TbT, const float* __restrict__ sub1,
               float* __restrict__ out){
  __shared__ __align__(16) char smem[41472];
  u16*  cw  = (u16*)smem;                       // [32][128] swizzled, 8 KB
  u16*  Pl  = (u16*)(smem + 8192);              // [32][512] swizzled, 32 KB
  float (*red)[32] = (float(*)[32])(smem + 40960);  // [4][32]
  float* avl = (float*)smem;                    // overlay after PV: [32][132]
  float* bvl = avl + 32*132;

  int bid = blockIdx.x;
  int id = (bid & 7) * 128 + (bid >> 3);        // XCD swizzle, nwg=1024
  int b = id >> 6, ctile = id & 63, c0 = ctile * 32;
  int w  = threadIdx.x >> 6, l = threadIdx.x & 63;
  int wq = w & 3, wc = w >> 2;
  int lj = l & 15, lg = l >> 4;

  // stage Cw tile [32 c][128 d] via gload_lds, pre-swizzled source
  {
    const char* gb = (const char*)(Cwb + ((size_t)(b*LC + c0))*DD);
    int off = w*1024 + l*16;
    int row = off >> 8, col = off & 255;
    int src = (row << 8) | (col ^ ((row & 7) << 4));
    GLOAD_LDS(gb + src, smem + off);
  }
  float s1v[8];
  #pragma unroll
  for (int f = 0; f < 8; ++f) s1v[f] = sub1[b*LQ + wq*128 + f*16 + lj];
  __syncthreads();

  // QK^T: S[c = wc*16 + lg*4 + r][q = wq*128 + f*16 + lj]
  f32x4 s[8];
  #pragma unroll
  for (int f = 0; f < 8; ++f) s[f] = (f32x4){0.f,0.f,0.f,0.f};
  #pragma unroll
  for (int ks = 0; ks < 4; ++ks) {
    bf16x8 ca = ldb8(swz(cw, wc*16 + lj, ks*64 + lg*16));
    #pragma unroll
    for (int f = 0; f < 8; ++f) {
      bf16x8 qv = ldb8(Qb + ((size_t)(b*LQ + wq*128 + f*16 + lj))*DD + ks*32 + lg*8);
      s[f] = MFMA(ca, qv, s[f]);
    }
  }

  // row max (q-direction): in-register over f, shfl over lj, LDS over wq
  float tm[4] = {-1e30f,-1e30f,-1e30f,-1e30f};
  #pragma unroll
  for (int f = 0; f < 8; ++f)
    #pragma unroll
    for (int r = 0; r < 4; ++r) { s[f][r] += s1v[f]; tm[r] = fmaxf(tm[r], s[f][r]); }
  #pragma unroll
  for (int r = 0; r < 4; ++r) {
    #pragma unroll
    for (int m = 1; m < 16; m <<= 1) tm[r] = fmaxf(tm[r], __shfl_xor(tm[r], m));
  }
  if (lj == 0) {
    #pragma unroll
    for (int r = 0; r < 4; ++r) red[wq][wc*16 + lg*4 + r] = tm[r];
  }
  __syncthreads();
  float mfin[4];
  #pragma unroll
  for (int r = 0; r < 4; ++r) {
    int row = wc*16 + lg*4 + r;
    mfin[r] = fmaxf(fmaxf(red[0][row], red[1][row]), fmaxf(red[2][row], red[3][row]));
  }
  __syncthreads();

  // exp + P->LDS (swizzled) + row sum
  float ps[4] = {0.f,0.f,0.f,0.f};
  #pragma unroll
  for (int f = 0; f < 8; ++f) {
    #pragma unroll
    for (int r = 0; r < 4; ++r) {
      float p = exp2f((s[f][r] - mfin[r]) * L2E);
      ps[r] += p;
      int row = wc*16 + lg*4 + r;
      int q   = wq*128 + f*16 + lj;
      *swzP(Pl, row, q*2) = f2bf(p);
    }
  }
  #pragma unroll
  for (int r = 0; r < 4; ++r) {
    #pragma unroll
    for (int m = 1; m < 16; m <<= 1) ps[r] += __shfl_xor(ps[r], m);
  }
  if (lj == 0) {
    #pragma unroll
    for (int r = 0; r < 4; ++r) red[wq][wc*16 + lg*4 + r] = ps[r];
  }
  __syncthreads();
  float linv[4];
  #pragma unroll
  for (int r = 0; r < 4; ++r) {
    int row = wc*16 + lg*4 + r;
    linv[r] = 1.0f / (red[0][row] + red[1][row] + red[2][row] + red[3][row]);
  }

  // PV: A/Bt[c = wc*16.., d = wq*32 + cf*16 + lj], k = q (512)
  f32x4 aA[2], aB[2];
  #pragma unroll
  for (int cf = 0; cf < 2; ++cf) { aA[cf] = (f32x4){0.f,0.f,0.f,0.f}; aB[cf] = (f32x4){0.f,0.f,0.f,0.f}; }
  #pragma unroll
  for (int ks = 0; ks < 16; ++ks) {
    bf16x8 pa = ldb8(swzP(Pl, wc*16 + lj, ks*64 + lg*16));
    #pragma unroll
    for (int cf = 0; cf < 2; ++cf) {
      size_t bo = ((size_t)(b*DD + wq*32 + cf*16 + lj))*LQ + ks*32 + lg*8;
      bf16x8 qv = ldb8(QbT + bo);
      bf16x8 tv = ldb8(TbT + bo);
      aA[cf] = MFMA(pa, qv, aA[cf]);
      aB[cf] = MFMA(pa, tv, aB[cf]);
    }
  }
  __syncthreads();   // done with cw/Pl; reuse as avl/bvl

  #pragma unroll
  for (int cf = 0; cf < 2; ++cf)
    #pragma unroll
    for (int r = 0; r < 4; ++r) {
      int row = wc*16 + lg*4 + r;
      int d   = wq*32 + cf*16 + lj;
      avl[row*132 + d] = aA[cf][r] * linv[r];
      bvl[row*132 + d] = aB[cf][r] * linv[r];
    }
  __syncthreads();

  // coalesced output: wave (seg = w&3, rh = w>>2) writes rows rh*16..+15 of segment seg
  int seg = w & 3, rh = w >> 2;
  for (int i = 0; i < 8; ++i) {
    int row = rh*16 + i*2 + (l >> 5), d4 = l & 31;
    size_t grow = (size_t)(b*LC + c0 + row);
    float4 o;
    if (seg == 0) {
      o = *reinterpret_cast<const float4*>(Cf + grow*DD + d4*4);
    } else if (seg == 1) {
      o = *reinterpret_cast<const float4*>(avl + row*132 + d4*4);
    } else if (seg == 2) {
      float4 c = *reinterpret_cast<const float4*>(Cf + grow*DD + d4*4);
      float4 a = *reinterpret_cast<const float4*>(avl + row*132 + d4*4);
      o.x = c.x*a.x; o.y = c.y*a.y; o.z = c.z*a.z; o.w = c.w*a.w;
    } else {
      float4 c = *reinterpret_cast<const float4*>(Cf + grow*DD + d4*4);
      float4 bb = *reinterpret_cast<const float4*>(bvl + row*132 + d4*4);
      o.x = c.x*bb.x; o.y = c.y*bb.y; o.z = c.z*bb.z; o.w = c.w*bb.w;
    }
    *reinterpret_cast<float4*>(out + grow*512 + seg*128 + d4*4) = o;
  }
}

// ---------------- launch ----------------
extern "C" void kernel_launch(void* const* d_in, const int* in_sizes, int n_in,
                              void* d_out, int out_size, void* d_ws, size_t ws_size,
                              hipStream_t stream) {
  const float* C     = (const float*)d_in[0];
  const float* Q     = (const float*)d_in[1];
  const float* w4C   = (const float*)d_in[4];
  const float* w4Q   = (const float*)d_in[5];
  const float* w4mlu = (const float*)d_in[6];
  float* out = (float*)d_out;

  char* ws = (char*)d_ws;
  size_t off = 0;
  auto alloc = [&](size_t bytes) -> void* {
    void* p = ws + off;
    off += (bytes + 255) & ~(size_t)255;
    return p;
  };
  float* sub0  = (float*)alloc((size_t)B_*LC*4);
  float* sub1  = (float*)alloc((size_t)B_*LQ*4);
  u16*   Cwb   = (u16*)  alloc((size_t)B_*LC*DD*2);
  u16*   CbT   = (u16*)  alloc((size_t)B_*DD*LC*2);
  u16*   Qb    = (u16*)  alloc((size_t)B_*LQ*DD*2);
  u16*   QbT   = (u16*)  alloc((size_t)B_*DD*LQ*2);
  u16*   TbT   = (u16*)  alloc((size_t)B_*DD*LQ*2);
  float* mPart = (float*)alloc((size_t)B_*8*SP*64*4);
  float* lPart = (float*)alloc((size_t)B_*8*SP*64*4);
  u16*   TaccP = (u16*)  alloc((size_t)B_*8*SP*64*DD*2);

  hipLaunchKernelGGL(prep, dim3(640), dim3(256), 0, stream,
                     C, Q, w4C, w4Q, w4mlu, Cwb, CbT, Qb, QbT, sub0, sub1);
  hipLaunchKernelGGL(flashT, dim3(2048), dim3(256), 0, stream,
                     Qb, Cwb, CbT, sub0, mPart, lPart, TaccP);
  hipLaunchKernelGGL(combineT, dim3(256), dim3(256), 0, stream,
                     mPart, lPart, TaccP, TbT);
  hipLaunchKernelGGL(fused_out, dim3(1024), dim3(512), 0, stream,
                     C, Cwb, Qb, QbT, TbT, sub1, out);
}

// Round 5
// 92.355 us; speedup vs baseline: 1.6072x; 1.6072x over previous
//
#include <hip/hip_runtime.h>

#define B_  16
#define LC  2048
#define LQ  512
#define DD  128
#define L2E 1.44269504088896340736f
#define SP  16

typedef __attribute__((ext_vector_type(8))) short bf16x8;
typedef __attribute__((ext_vector_type(4))) float f32x4;
typedef unsigned short u16;
typedef unsigned int   u32;

#define MFMA(a,b,c) __builtin_amdgcn_mfma_f32_16x16x32_bf16((a),(b),(c),0,0,0)

__device__ __forceinline__ u16 f2bf(float x){
  u32 u = __builtin_bit_cast(u32, x);
  u32 r = (u + 0x7FFFu + ((u >> 16) & 1u)) >> 16;
  return (u16)r;
}
__device__ __forceinline__ float bf2f(u16 h){
  u32 u = ((u32)h) << 16;
  return __builtin_bit_cast(float, u);
}
__device__ __forceinline__ bf16x8 ldb8(const u16* p){
  return *reinterpret_cast<const bf16x8*>(p);
}
// swizzled LDS read addr for a [rows][256B] tile: byte ^= (row&7)<<4
__device__ __forceinline__ const u16* swz(const u16* base, int row, int colb){
  return base + (row << 7) + ((colb ^ ((row & 7) << 4)) >> 1);
}
#define GLOAD_LDS(g, l) \
  __builtin_amdgcn_global_load_lds((const __attribute__((address_space(1))) void*)(g), \
                                   (__attribute__((address_space(3))) void*)(l), 16, 0, 0)

// ---------------- K0: bf16 staging + transposes + row-dots ----------------
__global__ void prep(const float* __restrict__ C, const float* __restrict__ Q,
                     const float* __restrict__ w4C, const float* __restrict__ w4Q,
                     const float* __restrict__ w4mlu,
                     u16* __restrict__ Cwb, u16* __restrict__ CbT,
                     u16* __restrict__ Qb,  u16* __restrict__ QbT,
                     float* __restrict__ sub0, float* __restrict__ sub1){
  __shared__ u16 tile[64][130];
  __shared__ float wl[128];
  int t = threadIdx.x, blk = blockIdx.x;
  int lane = t & 63;
  bool isC = blk < 512;
  if (t < 128) wl[t] = w4mlu[t];
  __syncthreads();
  float2 wv = reinterpret_cast<const float2*>(isC ? w4C : w4Q)[lane];
  if (isC) {
    int b = blk >> 5, ct = blk & 31, c0 = ct << 6;
    const float* src = C + ((size_t)(b*LC + c0))*DD;
    for (int k = 0; k < 16; ++k) {
      int idx = t + (k << 8);
      int r = idx >> 6, d2 = idx & 63;
      float2 v = reinterpret_cast<const float2*>(src + (size_t)r*DD)[d2];
      float sdot = v.x*wv.x + v.y*wv.y;
      #pragma unroll
      for (int o = 32; o > 0; o >>= 1) sdot += __shfl_xor(sdot, o);
      if (lane == 0) sub0[b*LC + c0 + r] = sdot;
      float cw0 = v.x * wl[2*d2], cw1 = v.y * wl[2*d2+1];
      size_t o = ((size_t)(b*LC + c0 + r))*DD + 2*d2;
      *reinterpret_cast<u32*>(Cwb + o) = (u32)f2bf(cw0) | ((u32)f2bf(cw1) << 16);
      tile[r][2*d2]   = f2bf(v.x);
      tile[r][2*d2+1] = f2bf(v.y);
    }
    __syncthreads();
    for (int k = 0; k < 8; ++k) {
      int ch = t + (k << 8);
      int d = ch >> 4, c4 = (ch & 15) << 2;
      u32 lo = (u32)tile[c4][d]   | ((u32)tile[c4+1][d] << 16);
      u32 hi = (u32)tile[c4+2][d] | ((u32)tile[c4+3][d] << 16);
      uint2 u; u.x = lo; u.y = hi;
      *reinterpret_cast<uint2*>(CbT + ((size_t)(b*DD + d))*LC + c0 + c4) = u;
    }
  } else {
    int bq = blk - 512;
    int b = bq >> 3, qt = bq & 7, q0 = qt << 6;
    const float* src = Q + ((size_t)(b*LQ + q0))*DD;
    for (int k = 0; k < 16; ++k) {
      int idx = t + (k << 8);
      int r = idx >> 6, d2 = idx & 63;
      float2 v = reinterpret_cast<const float2*>(src + (size_t)r*DD)[d2];
      float sdot = v.x*wv.x + v.y*wv.y;
      #pragma unroll
      for (int o = 32; o > 0; o >>= 1) sdot += __shfl_xor(sdot, o);
      if (lane == 0) sub1[b*LQ + q0 + r] = sdot;
      u16 h0 = f2bf(v.x), h1 = f2bf(v.y);
      size_t o = ((size_t)(b*LQ + q0 + r))*DD + 2*d2;
      *reinterpret_cast<u32*>(Qb + o) = (u32)h0 | ((u32)h1 << 16);
      tile[r][2*d2]   = h0;
      tile[r][2*d2+1] = h1;
    }
    __syncthreads();
    for (int k = 0; k < 8; ++k) {
      int ch = t + (k << 8);
      int d = ch >> 4, c4 = (ch & 15) << 2;
      u32 lo = (u32)tile[c4][d]   | ((u32)tile[c4+1][d] << 16);
      u32 hi = (u32)tile[c4+2][d] | ((u32)tile[c4+3][d] << 16);
      uint2 u; u.x = lo; u.y = hi;
      *reinterpret_cast<uint2*>(QbT + ((size_t)(b*DD + d))*LQ + q0 + c4) = u;
    }
  }
}

// ---------------- K1: flash column-softmax -> partial T ----------------
__global__ __launch_bounds__(256, 3)
void flashT(const u16* __restrict__ Qb, const u16* __restrict__ Cwb,
            const u16* __restrict__ CbT, const float* __restrict__ sub0,
            float* __restrict__ mPart, float* __restrict__ lPart,
            u16* __restrict__ TaccP){
  __shared__ __align__(16) u16 buf[128*128];
  __shared__ u16 Pl[64][136];
  int bid = blockIdx.x;
  int id = (bid & 7) * 256 + (bid >> 3);
  int b = id >> 7, qb = (id >> 4) & 7, sp = id & 15;
  int c0 = sp * 128;
  int w = threadIdx.x >> 6, l = threadIdx.x & 63;
  int lj = l & 15, lg = l >> 4;

  {
    const char* gb = (const char*)(Cwb + ((size_t)(b*LC + c0))*DD);
    #pragma unroll
    for (int i = 0; i < 8; ++i) {
      int off = (w*8 + i)*1024 + l*16;
      int row = off >> 8, col = off & 255;
      int src = (row << 8) | (col ^ ((row & 7) << 4));
      GLOAD_LDS(gb + src, (char*)buf + off);
    }
  }
  const u16* Qrow = Qb + ((size_t)(b*LQ + qb*64 + w*16 + lj))*DD;
  bf16x8 aq[4];
  #pragma unroll
  for (int k = 0; k < 4; ++k) aq[k] = ldb8(Qrow + k*32 + lg*8);
  float s0v[8];
  #pragma unroll
  for (int f = 0; f < 8; ++f) s0v[f] = sub0[b*LC + c0 + f*16 + lj];
  __syncthreads();

  f32x4 s[8];
  #pragma unroll
  for (int f = 0; f < 8; ++f) s[f] = (f32x4){0.f,0.f,0.f,0.f};
  #pragma unroll
  for (int ks = 0; ks < 4; ++ks) {
    #pragma unroll
    for (int f = 0; f < 8; ++f)
      s[f] = MFMA(aq[ks], ldb8(swz(buf, f*16 + lj, ks*64 + lg*16)), s[f]);
  }
  __syncthreads();

  {
    const char* gb = (const char*)CbT + ((size_t)b*DD)*LC*2 + (size_t)c0*2;
    #pragma unroll
    for (int i = 0; i < 8; ++i) {
      int off = (w*8 + i)*1024 + l*16;
      int row = off >> 8, col = off & 255;
      size_t src = (size_t)row*(LC*2) + (col ^ ((row & 7) << 4));
      GLOAD_LDS(gb + src, (char*)buf + off);
    }
  }

  float tm[4] = {-1e30f,-1e30f,-1e30f,-1e30f};
  #pragma unroll
  for (int f = 0; f < 8; ++f) {
    #pragma unroll
    for (int r = 0; r < 4; ++r) { s[f][r] += s0v[f]; tm[r] = fmaxf(tm[r], s[f][r]); }
  }
  #pragma unroll
  for (int r = 0; r < 4; ++r) {
    #pragma unroll
    for (int m = 1; m < 16; m <<= 1) tm[r] = fmaxf(tm[r], __shfl_xor(tm[r], m));
  }
  float psum[4] = {0.f,0.f,0.f,0.f};
  #pragma unroll
  for (int f = 0; f < 8; ++f) {
    #pragma unroll
    for (int r = 0; r < 4; ++r) {
      float p = exp2f((s[f][r] - tm[r]) * L2E);
      psum[r] += p;
      Pl[w*16 + lg*4 + r][f*16 + lj] = f2bf(p);
    }
  }
  #pragma unroll
  for (int r = 0; r < 4; ++r) {
    #pragma unroll
    for (int m = 1; m < 16; m <<= 1) psum[r] += __shfl_xor(psum[r], m);
  }
  int pbase = (b*8 + qb)*SP + sp;
  if (lj == 0) {
    #pragma unroll
    for (int r = 0; r < 4; ++r) {
      mPart[pbase*64 + w*16 + lg*4 + r] = tm[r];
      lPart[pbase*64 + w*16 + lg*4 + r] = psum[r];
    }
  }
  __syncthreads();

  f32x4 tacc[8];
  #pragma unroll
  for (int f = 0; f < 8; ++f) tacc[f] = (f32x4){0.f,0.f,0.f,0.f};
  #pragma unroll
  for (int ks = 0; ks < 4; ++ks) {
    bf16x8 ap = *reinterpret_cast<const bf16x8*>(&Pl[w*16 + lj][ks*32 + lg*8]);
    #pragma unroll
    for (int f = 0; f < 8; ++f)
      tacc[f] = MFMA(ap, ldb8(swz(buf, f*16 + lj, ks*64 + lg*16)), tacc[f]);
  }
  #pragma unroll
  for (int f = 0; f < 8; ++f) {
    ushort4 hv;
    hv.x = f2bf(tacc[f][0]); hv.y = f2bf(tacc[f][1]);
    hv.z = f2bf(tacc[f][2]); hv.w = f2bf(tacc[f][3]);
    *reinterpret_cast<ushort4*>(TaccP + (((size_t)pbase*4 + w)*8 + f)*256 + lj*16 + lg*4) = hv;
  }
}

// ---------------- K1b: combine c-split partials -> TbT ----------------
__global__ void combineT(const float* __restrict__ mPart, const float* __restrict__ lPart,
                         const u16* __restrict__ TaccP, u16* __restrict__ TbT){
  __shared__ float fac[SP][64];
  __shared__ u16 Tt[64][68];
  int blk = blockIdx.x;
  int b = blk >> 4, qb = (blk >> 1) & 7, dh = blk & 1;
  int t = threadIdx.x;
  int base = (b*8 + qb)*SP;
  if (t < 64) {
    float m_[SP], mm = -1e30f;
    #pragma unroll
    for (int p = 0; p < SP; ++p) { m_[p] = mPart[(base+p)*64 + t]; mm = fmaxf(mm, m_[p]); }
    float lt = 0.f, e[SP];
    #pragma unroll
    for (int p = 0; p < SP; ++p) {
      e[p] = exp2f((m_[p] - mm) * L2E);
      lt += lPart[(base+p)*64 + t] * e[p];
    }
    float il = 1.0f / lt;
    #pragma unroll
    for (int p = 0; p < SP; ++p) fac[p][t] = e[p] * il;
  }
  __syncthreads();
  int lj = t >> 4, lg = (t >> 2) & 3, r = t & 3;
  for (int w = 0; w < 4; ++w) {
    int q = w*16 + lg*4 + r;
    for (int fi = 0; fi < 4; ++fi) {
      int f = dh*4 + fi;
      float acc = 0.f;
      #pragma unroll
      for (int p = 0; p < SP; ++p)
        acc += bf2f(TaccP[(((size_t)(base+p)*4 + w)*8 + f)*256 + t]) * fac[p][q];
      Tt[q][fi*16 + lj] = f2bf(acc);
    }
  }
  __syncthreads();
  for (int k = 0; k < 4; ++k) {
    int ch = t + (k << 8); int dl = ch >> 4, q4 = (ch & 15) << 2;
    u32 lo = (u32)Tt[q4][dl]   | ((u32)Tt[q4+1][dl] << 16);
    u32 hi = (u32)Tt[q4+2][dl] | ((u32)Tt[q4+3][dl] << 16);
    uint2 u; u.x = lo; u.y = hi;
    *reinterpret_cast<uint2*>(TbT + ((size_t)(b*DD + dh*64 + dl))*LQ + qb*64 + q4) = u;
  }
}

// ---------------- K2: row-softmax + A + Bt + epilogue (all-LDS operands) ----
// grid 1024 = 16 b x 64 ctiles(32 c). 8 waves (512 thr).
// QK phase: wave = (wc = w>>2 c-half, wq = w&3 q-frag); q in 8 chunks of 64, LDS dbuf.
// PV phase: wave = (wc, wd = w&3 d-frag); q in 8 chunks of 64, A/B interleaved stage.
__global__ __launch_bounds__(512, 4)
void fused_out(const float* __restrict__ Cf, const u16* __restrict__ Cwb,
               const u16* __restrict__ Qb, const u16* __restrict__ QbT,
               const u16* __restrict__ TbT, const float* __restrict__ sub1,
               float* __restrict__ out){
  __shared__ __align__(16) char smem[74240];
  u16*  cw   = (u16*)smem;                       // [32][128] swz 256B rows, 8 KB
  char* stg  = smem + 8192;                      // 32 KB: QK dbuf 2x16KB / PV stgA+stgB
  u16*  Pl   = (u16*)(smem + 40960);             // [32][512] swz 1024B rows, 32 KB
  float (*red)[32] = (float(*)[32])(smem + 73728);
  float* avl = (float*)smem;                     // overlay after PV: [32][132] x2
  float* bvl = avl + 32*132;

  int bid = blockIdx.x;
  int id = (bid & 7) * 128 + (bid >> 3);         // XCD swizzle, nwg=1024
  int b = id >> 6, ctile = id & 63, c0 = ctile * 32;
  int tid = threadIdx.x;
  int w  = tid >> 6, l = tid & 63;
  int wc = w >> 2, wq = w & 3;                   // wq doubles as wd in PV
  int lj = l & 15, lg = l >> 4;

  // ---- stage cw tile [32 c][256B] (1 granule/thread, pre-swizzled source)
  {
    const char* gb = (const char*)(Cwb + ((size_t)(b*LC + c0))*DD);
    int off = tid*16;
    int row = off >> 8, col = off & 255;
    GLOAD_LDS(gb + ((row << 8) | (col ^ ((row & 7) << 4))), smem + off);
  }
  // ---- stage Q chunk 0 -> buf0 (2 granules/thread)
  {
    const char* gb = (const char*)(Qb + ((size_t)(b*LQ + 0))*DD);
    #pragma unroll
    for (int i = 0; i < 2; ++i) {
      int off = i*8192 + tid*16;
      int row = off >> 8, col = off & 255;
      GLOAD_LDS(gb + ((row << 8) | (col ^ ((row & 7) << 4))), stg + off);
    }
  }
  float s1v[8];
  #pragma unroll
  for (int j = 0; j < 8; ++j) s1v[j] = sub1[b*LQ + j*64 + wq*16 + lj];
  __syncthreads();

  // hoisted A-fragments (Cw rows wc*16+lj)
  bf16x8 ca[4];
  {
    int row = wc*16 + lj;
    #pragma unroll
    for (int ks = 0; ks < 4; ++ks)
      ca[ks] = ldb8(cw + (row << 7) + (((ks*64 + lg*16) ^ ((row & 7) << 4)) >> 1));
  }

  // ---- QK: 8 chunks of 64 q, double-buffered
  f32x4 s[8];
  #pragma unroll
  for (int j = 0; j < 8; ++j) s[j] = (f32x4){0.f,0.f,0.f,0.f};
  #pragma unroll
  for (int j = 0; j < 8; ++j) {
    if (j < 7) {
      const char* gb = (const char*)(Qb + ((size_t)(b*LQ + (j+1)*64))*DD);
      char* db = stg + ((j+1)&1)*16384;
      #pragma unroll
      for (int i = 0; i < 2; ++i) {
        int off = i*8192 + tid*16;
        int row = off >> 8, col = off & 255;
        GLOAD_LDS(gb + ((row << 8) | (col ^ ((row & 7) << 4))), db + off);
      }
    }
    const u16* qs = (const u16*)(stg + (j&1)*16384);
    int q_ = wq*16 + lj;
    #pragma unroll
    for (int ks = 0; ks < 4; ++ks) {
      bf16x8 qv = ldb8(qs + (q_ << 7) + (((ks*64 + lg*16) ^ ((q_ & 7) << 4)) >> 1));
      s[j] = MFMA(ca[ks], qv, s[j]);
    }
    __syncthreads();   // chunk j+1 staged & buf (j&1) free
  }

  // ---- early-issue PV chunk 0 stage (latency hidden under softmax)
  {
    const char* gq = (const char*)QbT + ((size_t)b*DD)*LQ*2;
    const char* gt = (const char*)TbT + ((size_t)b*DD)*LQ*2;
    #pragma unroll
    for (int i = 0; i < 2; ++i) {
      int off = i*8192 + tid*16;
      int row = off >> 7, col = off & 127;
      size_t src = (size_t)row*1024 + (col ^ ((row & 7) << 4));
      GLOAD_LDS(gq + src, stg + off);
      GLOAD_LDS(gt + src, stg + 16384 + off);
    }
  }

  // ---- row softmax over q (rows c = wc*16+lg*4+r)
  float tm[4] = {-1e30f,-1e30f,-1e30f,-1e30f};
  #pragma unroll
  for (int j = 0; j < 8; ++j)
    #pragma unroll
    for (int r = 0; r < 4; ++r) { s[j][r] += s1v[j]; tm[r] = fmaxf(tm[r], s[j][r]); }
  #pragma unroll
  for (int r = 0; r < 4; ++r) {
    #pragma unroll
    for (int m = 1; m < 16; m <<= 1) tm[r] = fmaxf(tm[r], __shfl_xor(tm[r], m));
  }
  if (lj == 0) {
    #pragma unroll
    for (int r = 0; r < 4; ++r) red[wq][wc*16 + lg*4 + r] = tm[r];
  }
  __syncthreads();
  float mfin[4];
  #pragma unroll
  for (int r = 0; r < 4; ++r) {
    int row = wc*16 + lg*4 + r;
    mfin[r] = fmaxf(fmaxf(red[0][row], red[1][row]), fmaxf(red[2][row], red[3][row]));
  }
  __syncthreads();
  float ps[4] = {0.f,0.f,0.f,0.f};
  #pragma unroll
  for (int j = 0; j < 8; ++j) {
    #pragma unroll
    for (int r = 0; r < 4; ++r) {
      float p = exp2f((s[j][r] - mfin[r]) * L2E);
      ps[r] += p;
      int c = wc*16 + lg*4 + r;
      int qcol = j*64 + wq*16 + lj;
      Pl[(c << 9) + ((((qcol << 1) ^ ((c & 7) << 4))) >> 1)] = f2bf(p);
    }
  }
  #pragma unroll
  for (int r = 0; r < 4; ++r) {
    #pragma unroll
    for (int m = 1; m < 16; m <<= 1) ps[r] += __shfl_xor(ps[r], m);
  }
  if (lj == 0) {
    #pragma unroll
    for (int r = 0; r < 4; ++r) red[wq][wc*16 + lg*4 + r] = ps[r];
  }
  __syncthreads();   // sums ready + Pl visible + PV chunk0 staged
  float linv[4];
  #pragma unroll
  for (int r = 0; r < 4; ++r) {
    int row = wc*16 + lg*4 + r;
    linv[r] = 1.0f / (red[0][row] + red[1][row] + red[2][row] + red[3][row]);
  }

  // ---- PV: 8 chunks of 64 q; A/B phase-interleaved single-buffer pipeline
  // wave role: (wc, wd = wq); acc rows c = wc*16+lg*4+r, cols d = wd*32+cf*16+lj
  f32x4 aA[2], aB[2];
  #pragma unroll
  for (int cf = 0; cf < 2; ++cf) { aA[cf] = (f32x4){0.f,0.f,0.f,0.f}; aB[cf] = (f32x4){0.f,0.f,0.f,0.f}; }
  int wd = wq;
  const u16* stgA = (const u16*)stg;
  const u16* stgB = (const u16*)(stg + 16384);
  int crow = wc*16 + lj;
  #pragma unroll
  for (int k = 0; k < 8; ++k) {
    // A-fragments from Pl for this k-chunk (used by both phases)
    bf16x8 pa[2];
    #pragma unroll
    for (int ks2 = 0; ks2 < 2; ++ks2) {
      int qbyte = k*128 + ks2*64 + lg*16;
      pa[ks2] = ldb8(Pl + (crow << 9) + ((qbyte ^ ((crow & 7) << 4)) >> 1));
    }
    // phase A: Q-side MFMAs from stgA
    #pragma unroll
    for (int ks2 = 0; ks2 < 2; ++ks2)
      #pragma unroll
      for (int cf = 0; cf < 2; ++cf) {
        int drow = wd*32 + cf*16 + lj;
        bf16x8 bv = ldb8(stgA + (drow << 6) + (((ks2*64 + lg*16) ^ ((drow & 7) << 4)) >> 1));
        aA[cf] = MFMA(pa[ks2], bv, aA[cf]);
      }
    __syncthreads();                     // stgA free; TbT(k) ready
    if (k < 7) {                         // issue QbT(k+1) -> stgA
      const char* gq = (const char*)QbT + ((size_t)b*DD)*LQ*2 + (size_t)(k+1)*128;
      #pragma unroll
      for (int i = 0; i < 2; ++i) {
        int off = i*8192 + tid*16;
        int row = off >> 7, col = off & 127;
        GLOAD_LDS(gq + (size_t)row*1024 + (col ^ ((row & 7) << 4)), stg + off);
      }
    }
    // phase B: T-side MFMAs from stgB
    #pragma unroll
    for (int ks2 = 0; ks2 < 2; ++ks2)
      #pragma unroll
      for (int cf = 0; cf < 2; ++cf) {
        int drow = wd*32 + cf*16 + lj;
        bf16x8 bv = ldb8(stgB + (drow << 6) + (((ks2*64 + lg*16) ^ ((drow & 7) << 4)) >> 1));
        aB[cf] = MFMA(pa[ks2], bv, aB[cf]);
      }
    __syncthreads();                     // stgB free; QbT(k+1) ready
    if (k < 7) {                         // issue TbT(k+1) -> stgB
      const char* gt = (const char*)TbT + ((size_t)b*DD)*LQ*2 + (size_t)(k+1)*128;
      #pragma unroll
      for (int i = 0; i < 2; ++i) {
        int off = i*8192 + tid*16;
        int row = off >> 7, col = off & 127;
        GLOAD_LDS(gt + (size_t)row*1024 + (col ^ ((row & 7) << 4)), stg + 16384 + off);
      }
    }
  }
  __syncthreads();   // all PV reads done; reuse smem as avl/bvl

  #pragma unroll
  for (int cf = 0; cf < 2; ++cf)
    #pragma unroll
    for (int r = 0; r < 4; ++r) {
      int row = wc*16 + lg*4 + r;
      int d   = wd*32 + cf*16 + lj;
      avl[row*132 + d] = aA[cf][r] * linv[r];
      bvl[row*132 + d] = aB[cf][r] * linv[r];
    }
  __syncthreads();

  // coalesced output: wave (seg = w&3, rh = w>>2) writes rows rh*16..+15 of segment seg
  int seg = w & 3, rh = w >> 2;
  for (int i = 0; i < 8; ++i) {
    int row = rh*16 + i*2 + (l >> 5), d4 = l & 31;
    size_t grow = (size_t)(b*LC + c0 + row);
    float4 o;
    if (seg == 0) {
      o = *reinterpret_cast<const float4*>(Cf + grow*DD + d4*4);
    } else if (seg == 1) {
      o = *reinterpret_cast<const float4*>(avl + row*132 + d4*4);
    } else if (seg == 2) {
      float4 c = *reinterpret_cast<const float4*>(Cf + grow*DD + d4*4);
      float4 a = *reinterpret_cast<const float4*>(avl + row*132 + d4*4);
      o.x = c.x*a.x; o.y = c.y*a.y; o.z = c.z*a.z; o.w = c.w*a.w;
    } else {
      float4 c = *reinterpret_cast<const float4*>(Cf + grow*DD + d4*4);
      float4 bb = *reinterpret_cast<const float4*>(bvl + row*132 + d4*4);
      o.x = c.x*bb.x; o.y = c.y*bb.y; o.z = c.z*bb.z; o.w = c.w*bb.w;
    }
    *reinterpret_cast<float4*>(out + grow*512 + seg*128 + d4*4) = o;
  }
}

// ---------------- launch ----------------
extern "C" void kernel_launch(void* const* d_in, const int* in_sizes, int n_in,
                              void* d_out, int out_size, void* d_ws, size_t ws_size,
                              hipStream_t stream) {
  const float* C     = (const float*)d_in[0];
  const float* Q     = (const float*)d_in[1];
  const float* w4C   = (const float*)d_in[4];
  const float* w4Q   = (const float*)d_in[5];
  const float* w4mlu = (const float*)d_in[6];
  float* out = (float*)d_out;

  char* ws = (char*)d_ws;
  size_t off = 0;
  auto alloc = [&](size_t bytes) -> void* {
    void* p = ws + off;
    off += (bytes + 255) & ~(size_t)255;
    return p;
  };
  float* sub0  = (float*)alloc((size_t)B_*LC*4);
  float* sub1  = (float*)alloc((size_t)B_*LQ*4);
  u16*   Cwb   = (u16*)  alloc((size_t)B_*LC*DD*2);
  u16*   CbT   = (u16*)  alloc((size_t)B_*DD*LC*2);
  u16*   Qb    = (u16*)  alloc((size_t)B_*LQ*DD*2);
  u16*   QbT   = (u16*)  alloc((size_t)B_*DD*LQ*2);
  u16*   TbT   = (u16*)  alloc((size_t)B_*DD*LQ*2);
  float* mPart = (float*)alloc((size_t)B_*8*SP*64*4);
  float* lPart = (float*)alloc((size_t)B_*8*SP*64*4);
  u16*   TaccP = (u16*)  alloc((size_t)B_*8*SP*64*DD*2);

  hipLaunchKernelGGL(prep, dim3(640), dim3(256), 0, stream,
                     C, Q, w4C, w4Q, w4mlu, Cwb, CbT, Qb, QbT, sub0, sub1);
  hipLaunchKernelGGL(flashT, dim3(2048), dim3(256), 0, stream,
                     Qb, Cwb, CbT, sub0, mPart, lPart, TaccP);
  hipLaunchKernelGGL(combineT, dim3(256), dim3(256), 0, stream,
                     mPart, lPart, TaccP, TbT);
  hipLaunchKernelGGL(fused_out, dim3(1024), dim3(512), 0, stream,
                     C, Cwb, Qb, QbT, TbT, sub1, out);
}